// Round 9
// baseline (780.661 us; speedup 1.0000x reference)
//
#include <hip/hip_runtime.h>
#include <hip/hip_bf16.h>
#include <cstdint>
#include <cstddef>

namespace {
constexpr int B = 512, S = 200, D = 256, H = 4, DH = 64, NI = 100000;
constexpr float EPS = 1e-3f;
constexpr float SCALE = 0.125f;  // 1/sqrt(DH)
}

typedef __attribute__((ext_vector_type(8))) short bf16x8;
typedef __attribute__((ext_vector_type(4))) float f32x4;

__device__ inline unsigned short f2b(float f) {
  union { float f; unsigned int u; } v; v.f = f;
  unsigned int r = v.u + 0x7FFFu + ((v.u >> 16) & 1u);
  return (unsigned short)(r >> 16);
}

__device__ inline float b2f(unsigned short u) {
  union { unsigned int i; float f; } x; x.i = (unsigned int)u << 16; return x.f;
}

__device__ inline bf16x8 pack8(float4 a, float4 b) {
  bf16x8 r;
  r[0] = (short)f2b(a.x); r[1] = (short)f2b(a.y); r[2] = (short)f2b(a.z); r[3] = (short)f2b(a.w);
  r[4] = (short)f2b(b.x); r[5] = (short)f2b(b.y); r[6] = (short)f2b(b.z); r[7] = (short)f2b(b.w);
  return r;
}

__device__ inline ushort4 pack4(float4 a) {
  ushort4 r;
  r.x = f2b(a.x); r.y = f2b(a.y); r.z = f2b(a.z); r.w = f2b(a.w);
  return r;
}

__device__ inline float4 unpack4(ushort4 u) {
  float4 r; r.x = b2f(u.x); r.y = b2f(u.y); r.z = b2f(u.z); r.w = b2f(u.w); return r;
}

__device__ inline void gload_lds16(const unsigned short* g, unsigned short* l) {
  __builtin_amdgcn_global_load_lds((const __attribute__((address_space(1))) void*)g,
                                   (__attribute__((address_space(3))) void*)l, 16, 0, 0);
}

// ------- hidden weights [K][N] fp32 -> WT bf16 [w][N][K], w = blk*4+{q,k,v,d}
__global__ void cvt_wt_k(const float* __restrict__ wq, const float* __restrict__ wk,
                         const float* __restrict__ wv, const float* __restrict__ wd,
                         unsigned short* __restrict__ dst) {
  const int t = blockIdx.x * 256 + threadIdx.x;  // 131072 total
  const int w = t >> 14, rem = t & 16383;
  const int k = rem >> 6, n4 = (rem & 63) * 4;
  const int blk = w >> 2, which = w & 3;
  const float* src = (which == 0 ? wq : which == 1 ? wk : which == 2 ? wv : wd) + blk * 65536;
  const float4 v = *(const float4*)(src + k * 256 + n4);
  unsigned short* d = dst + w * 65536;
  d[(n4 + 0) * 256 + k] = f2b(v.x);
  d[(n4 + 1) * 256 + k] = f2b(v.y);
  d[(n4 + 2) * 256 + k] = f2b(v.z);
  d[(n4 + 3) * 256 + k] = f2b(v.w);
}

// ------- embed + pos, fused with ln1 of layer 0: wave-per-row --------------
__global__ __launch_bounds__(256) void embed_ln_k(const int* __restrict__ ids,
                                                  const float* __restrict__ ie,
                                                  const float* __restrict__ pe,
                                                  const float* __restrict__ g1,
                                                  const float* __restrict__ b1,
                                                  unsigned short* __restrict__ seq_bf,
                                                  unsigned short* __restrict__ x_bf) {
  const int row = blockIdx.x * 4 + (threadIdx.x >> 6);
  const int lane = threadIdx.x & 63;
  const int id = ids[row];
  const int s = row % S;
  float4 v = *(const float4*)(ie + (size_t)id * D + (lane << 2));
  const float4 p = *(const float4*)(pe + (size_t)s * D + (lane << 2));
  v.x += p.x; v.y += p.y; v.z += p.z; v.w += p.w;
  *(ushort4*)(seq_bf + (size_t)row * D + (lane << 2)) = pack4(v);
  const float4 vb = unpack4(pack4(v));
  float su = vb.x + vb.y + vb.z + vb.w;
  float ss = vb.x * vb.x + vb.y * vb.y + vb.z * vb.z + vb.w * vb.w;
#pragma unroll
  for (int off = 32; off; off >>= 1) {
    su += __shfl_xor(su, off);
    ss += __shfl_xor(ss, off);
  }
  const float mean = su * (1.f / D);
  const float rs = rsqrtf(ss * (1.f / D) - mean * mean + EPS);
  const float4 gv = *(const float4*)(g1 + (lane << 2));
  const float4 bv = *(const float4*)(b1 + (lane << 2));
  float4 o;
  o.x = (vb.x - mean) * rs * gv.x + bv.x;
  o.y = (vb.y - mean) * rs * gv.y + bv.y;
  o.z = (vb.z - mean) * rs * gv.z + bv.z;
  o.w = (vb.w - mean) * rs * gv.w + bv.w;
  *(ushort4*)(x_bf + (size_t)row * D + (lane << 2)) = pack4(o);
}

// ---------------- wave-per-row LayerNorm, bf16 in -> bf16 out (semb) -------
__global__ __launch_bounds__(256) void ln_bf_k(const unsigned short* __restrict__ in,
                                               size_t in_stride,
                                               const float* __restrict__ g, const float* __restrict__ b,
                                               unsigned short* __restrict__ outp, int nrows) {
  const int row = blockIdx.x * 4 + (threadIdx.x >> 6);
  if (row >= nrows) return;
  const int lane = threadIdx.x & 63;
  const float4 v = unpack4(*(const ushort4*)(in + (size_t)row * in_stride + (lane << 2)));
  float s = v.x + v.y + v.z + v.w;
  float ss = v.x * v.x + v.y * v.y + v.z * v.z + v.w * v.w;
#pragma unroll
  for (int off = 32; off; off >>= 1) {
    s += __shfl_xor(s, off);
    ss += __shfl_xor(ss, off);
  }
  const float mean = s * (1.f / D);
  const float rs = rsqrtf(ss * (1.f / D) - mean * mean + EPS);
  const float4 gv = *(const float4*)(g + (lane << 2));
  const float4 bv = *(const float4*)(b + (lane << 2));
  float4 o;
  o.x = (v.x - mean) * rs * gv.x + bv.x;
  o.y = (v.y - mean) * rs * gv.y + bv.y;
  o.z = (v.z - mean) * rs * gv.z + bv.z;
  o.w = (v.w - mean) * rs * gv.w + bv.w;
  *(ushort4*)(outp + (size_t)row * D + (lane << 2)) = pack4(o);
}

// ------- fused: x2 = x_bf + o_bf (bf16 out) ; t = ln2(x2) ------------------
__global__ __launch_bounds__(256) void ln2x2_k(const unsigned short* __restrict__ x_bf,
                                               const unsigned short* __restrict__ o_bf,
                                               const float* __restrict__ g2, const float* __restrict__ b2,
                                               unsigned short* __restrict__ x2b,
                                               unsigned short* __restrict__ t_bf, int nrows) {
  const int row = blockIdx.x * 4 + (threadIdx.x >> 6);
  if (row >= nrows) return;
  const int lane = threadIdx.x & 63;
  const float4 xv = unpack4(*(const ushort4*)(x_bf + (size_t)row * D + (lane << 2)));
  const float4 ov = unpack4(*(const ushort4*)(o_bf + (size_t)row * D + (lane << 2)));
  float4 x2;
  x2.x = xv.x + ov.x; x2.y = xv.y + ov.y; x2.z = xv.z + ov.z; x2.w = xv.w + ov.w;
  *(ushort4*)(x2b + (size_t)row * D + (lane << 2)) = pack4(x2);
  float s2 = x2.x + x2.y + x2.z + x2.w;
  float ss2 = x2.x * x2.x + x2.y * x2.y + x2.z * x2.z + x2.w * x2.w;
#pragma unroll
  for (int off = 32; off; off >>= 1) {
    s2 += __shfl_xor(s2, off);
    ss2 += __shfl_xor(ss2, off);
  }
  const float mean2 = s2 * (1.f / D);
  const float rs2 = rsqrtf(ss2 * (1.f / D) - mean2 * mean2 + EPS);
  const float4 g2v = *(const float4*)(g2 + (lane << 2));
  const float4 b2v = *(const float4*)(b2 + (lane << 2));
  float4 t;
  t.x = (x2.x - mean2) * rs2 * g2v.x + b2v.x;
  t.y = (x2.y - mean2) * rs2 * g2v.y + b2v.y;
  t.z = (x2.z - mean2) * rs2 * g2v.z + b2v.z;
  t.w = (x2.w - mean2) * rs2 * g2v.w + b2v.w;
  *(ushort4*)(t_bf + (size_t)row * D + (lane << 2)) = pack4(t);
}

// -------- full-N hidden GEMM: C[M,256] = A[M,256] @ Wt[256,256]^T (+bias) --
template <int RELU, int UPD, int LN1>
__global__ __launch_bounds__(512) void bgemm2_k(const unsigned short* __restrict__ A,
                                                const unsigned short* __restrict__ Wt,
                                                const float* __restrict__ bias,
                                                unsigned short* __restrict__ Cbf,
                                                const unsigned short* __restrict__ x2b,
                                                const int* __restrict__ ids, float osc,
                                                const float* __restrict__ g1,
                                                const float* __restrict__ b1,
                                                unsigned short* __restrict__ x1) {
  __shared__ unsigned short As[128 * 64];
  __shared__ unsigned short Bs[256 * 64];
  const int tid = threadIdx.x, w = tid >> 6, lane = tid & 63;
  const int kb = lane >> 4, ln = lane & 15;
  const int m0 = blockIdx.x * 128;
  const int wm = w & 1, wn = w >> 1;

  f32x4 acc[4][4];
#pragma unroll
  for (int i = 0; i < 4; ++i)
#pragma unroll
    for (int j = 0; j < 4; ++j) acc[i][j] = (f32x4){0.f, 0.f, 0.f, 0.f};

  for (int ks = 0; ks < 4; ++ks) {
    const int ko = ks * 64;
#pragma unroll
    for (int r = 0; r < 2; ++r) {
      const int g = (w * 2 + r) * 64 + lane;
      const int row = g >> 3, gc = g & 7;
      gload_lds16(A + (size_t)(m0 + row) * 256 + ko + ((gc ^ (row & 7)) << 3),
                  As + (size_t)(w * 2 + r) * 512);
    }
#pragma unroll
    for (int r = 0; r < 4; ++r) {
      const int g = (w * 4 + r) * 64 + lane;
      const int row = g >> 3, gc = g & 7;
      gload_lds16(Wt + (size_t)row * 256 + ko + ((gc ^ (row & 7)) << 3),
                  Bs + (size_t)(w * 4 + r) * 512);
    }
    __syncthreads();
#pragma unroll
    for (int h = 0; h < 2; ++h) {
      bf16x8 af[4], bfr[4];
#pragma unroll
      for (int i = 0; i < 4; ++i) {
        const int ar = wm * 64 + i * 16 + ln;
        af[i] = *(const bf16x8*)(As + ar * 64 + (((h * 64 + kb * 16) ^ ((ar & 7) << 4)) >> 1));
        const int br = wn * 64 + i * 16 + ln;
        bfr[i] = *(const bf16x8*)(Bs + br * 64 + (((h * 64 + kb * 16) ^ ((br & 7) << 4)) >> 1));
      }
#pragma unroll
      for (int i = 0; i < 4; ++i)
#pragma unroll
        for (int j = 0; j < 4; ++j)
          acc[i][j] = __builtin_amdgcn_mfma_f32_16x16x32_bf16(af[i], bfr[j], acc[i][j], 0, 0, 0);
    }
    __syncthreads();
  }

  const int crow0 = m0 + wm * 64 + kb * 4;
  const int ccol0 = wn * 64 + ln;
  float mk[4][4];
  if (UPD) {
#pragma unroll
    for (int i = 0; i < 4; ++i)
#pragma unroll
      for (int r = 0; r < 4; ++r) mk[i][r] = (ids[crow0 + i * 16 + r] != NI) ? 1.f : 0.f;
  }
#pragma unroll
  for (int j = 0; j < 4; ++j) {
    const int col = ccol0 + j * 16;
    const float bj = bias[col];
#pragma unroll
    for (int i = 0; i < 4; ++i) {
#pragma unroll
      for (int r = 0; r < 4; ++r) {
        const int row = crow0 + i * 16 + r;
        float v = (acc[i][j][r] + bj) * osc;
        if (RELU) v = fmaxf(v, 0.f);
        if (UPD) v = (v + b2f(x2b[(size_t)row * 256 + col])) * mk[i][r];
        const unsigned short vb = f2b(v);
        Cbf[(size_t)row * 256 + col] = vb;
        if (LN1) acc[i][j][r] = b2f(vb);
      }
    }
  }

  if (LN1) {
    float s_[4][4], ss_[4][4];
#pragma unroll
    for (int i = 0; i < 4; ++i)
#pragma unroll
      for (int r = 0; r < 4; ++r) {
        float s = 0.f, ss = 0.f;
#pragma unroll
        for (int j = 0; j < 4; ++j) { const float v = acc[i][j][r]; s += v; ss += v * v; }
#pragma unroll
        for (int off = 1; off < 16; off <<= 1) {
          s += __shfl_xor(s, off);
          ss += __shfl_xor(ss, off);
        }
        s_[i][r] = s; ss_[i][r] = ss;
      }
    float* red = (float*)As;
    if (ln == 0) {
#pragma unroll
      for (int i = 0; i < 4; ++i)
#pragma unroll
        for (int r = 0; r < 4; ++r) {
          const int rl = wm * 64 + kb * 4 + i * 16 + r;
          red[rl * 8 + wn * 2 + 0] = s_[i][r];
          red[rl * 8 + wn * 2 + 1] = ss_[i][r];
        }
    }
    __syncthreads();
#pragma unroll
    for (int i = 0; i < 4; ++i)
#pragma unroll
      for (int r = 0; r < 4; ++r) {
        const int rl = wm * 64 + kb * 4 + i * 16 + r;
        float S = 0.f, SS = 0.f;
#pragma unroll
        for (int q = 0; q < 4; ++q) { S += red[rl * 8 + q * 2]; SS += red[rl * 8 + q * 2 + 1]; }
        const float mean = S * (1.f / D);
        s_[i][r] = mean;
        ss_[i][r] = rsqrtf(SS * (1.f / D) - mean * mean + EPS);
      }
#pragma unroll
    for (int j = 0; j < 4; ++j) {
      const int col = ccol0 + j * 16;
      const float gc = g1[col], bc = b1[col];
#pragma unroll
      for (int i = 0; i < 4; ++i) {
#pragma unroll
        for (int r = 0; r < 4; ++r) {
          const int row = crow0 + i * 16 + r;
          const float xv = (acc[i][j][r] - s_[i][r]) * ss_[i][r] * gc + bc;
          x1[(size_t)row * 256 + col] = f2b(xv);
        }
      }
    }
  }
}

// ------- logits GEMM: C[M,N] f32 = A(bf16) @ W(f32->bf16 reg-staged)^T ------
__global__ __launch_bounds__(256) void bgemm3_k(const unsigned short* __restrict__ A,
                                                const float* __restrict__ Wf,
                                                float* __restrict__ C, int M, int N) {
  __shared__ unsigned short As[128 * 64];
  __shared__ unsigned short Bs[128 * 64];
  const int tid = threadIdx.x, w = tid >> 6, lane = tid & 63;
  const int kb = lane >> 4, ln = lane & 15;
  const int m0 = blockIdx.x * 128;
  const int n0 = blockIdx.y * 128;
  const int wm = w & 1, wn = w >> 1;
  const int rl = lane >> 3;
  const int cb = (lane & 7) << 4;

  f32x4 acc[4][4];
#pragma unroll
  for (int i = 0; i < 4; ++i)
#pragma unroll
    for (int j = 0; j < 4; ++j) acc[i][j] = (f32x4){0.f, 0.f, 0.f, 0.f};

  for (int ks = 0; ks < 4; ++ks) {
    const int ko = ks * 64;
#pragma unroll
    for (int c = 0; c < 4; ++c) {
      const int arow = w * 32 + c * 8 + rl;
      const int sw = (arow & 7) << 4;
      const int cu = (cb ^ sw) >> 1;
      gload_lds16(A + (size_t)(m0 + arow) * 256 + ko + cu, As + (w * 32 + c * 8) * 64);
    }
#pragma unroll
    for (int c = 0; c < 4; ++c) {
      const int g = c * 256 + tid;
      const int row = g >> 3, gcs = g & 7;
      int br = n0 + row; if (br > N - 1) br = N - 1;
      const float* src = Wf + (size_t)br * 256 + ko + gcs * 8;
      const float4 f0 = *(const float4*)src;
      const float4 f1 = *(const float4*)(src + 4);
      *(bf16x8*)(Bs + row * 64 + ((gcs ^ (row & 7)) << 3)) = pack8(f0, f1);
    }
    __syncthreads();
#pragma unroll
    for (int h = 0; h < 2; ++h) {
      bf16x8 af[4], bfr[4];
#pragma unroll
      for (int i = 0; i < 4; ++i) {
        const int ar = wm * 64 + i * 16 + ln;
        af[i] = *(const bf16x8*)(As + ar * 64 + (((h * 64 + kb * 16) ^ ((ar & 7) << 4)) >> 1));
        const int br = wn * 64 + i * 16 + ln;
        bfr[i] = *(const bf16x8*)(Bs + br * 64 + (((h * 64 + kb * 16) ^ ((br & 7) << 4)) >> 1));
      }
#pragma unroll
      for (int i = 0; i < 4; ++i)
#pragma unroll
        for (int j = 0; j < 4; ++j)
          acc[i][j] = __builtin_amdgcn_mfma_f32_16x16x32_bf16(af[i], bfr[j], acc[i][j], 0, 0, 0);
    }
    __syncthreads();
  }

  const int crow0 = m0 + wm * 64 + kb * 4;
  const int ccol0 = n0 + wn * 64 + ln;
#pragma unroll
  for (int j = 0; j < 4; ++j) {
    const int col = ccol0 + j * 16;
    if (col >= N) continue;
#pragma unroll
    for (int i = 0; i < 4; ++i) {
#pragma unroll
      for (int r = 0; r < 4; ++r) {
        const int row = crow0 + i * 16 + r;
        C[(size_t)row * N + col] = acc[i][j][r];
      }
    }
  }
}

// ---------------- MFMA causal attention: fragment-major LDS + causal skip --
// Chunk c handles queries [c*16, c*16+16); only key-tiles t <= tmax(c) are
// computed (tmax = min(12, c|1), odd-rounded so each 32-key PV granule's two
// P tiles are both written). PV runs kt <= c>>1; 192..207 tail only at c=12.
// Snake chunk assignment balances per-wave cost (c+1): w0:{12,5,4} w1:{11,6,3}
// w2:{10,7,2} w3:{9,8,1,0}. Guards are wave-uniform (scalar branches).
__global__ __launch_bounds__(256) void attn_k(const unsigned short* __restrict__ Q,
                                              const unsigned short* __restrict__ Kg,
                                              const unsigned short* __restrict__ Vg,
                                              unsigned short* __restrict__ O) {
  __shared__ unsigned short Ks[13312];      // [t*2+h][lane] granules of 8
  __shared__ unsigned short Vt[13312];      // frag-major V^T + 192..207 half tiles
  __shared__ unsigned short Ps[4 * 3328];   // per-wave P, 208 keys
  const int b = blockIdx.x >> 2;
  const int h = blockIdx.x & 3;
  const int tid = threadIdx.x, w = tid >> 6, lane = tid & 63;
  const int kb = lane >> 4, ln = lane & 15;
  const size_t base = (size_t)b * S * D + h * DH;

  for (int s = w; s < 26; s += 4) {
    const int t = s >> 1, h2 = s & 1;
    int krow = t * 16 + ln; if (krow > S - 1) krow = S - 1;
    gload_lds16(Kg + base + (size_t)krow * D + h2 * 32 + kb * 8, Ks + s * 512);
  }
  for (int g = tid; g < 200 * 8; g += 256) {
    const int key = g >> 3, d0 = (g & 7) * 8;
    const bf16x8 v = *(const bf16x8*)(Vg + base + (size_t)key * D + d0);
#pragma unroll
    for (int i = 0; i < 8; ++i) {
      const int d = d0 + i, ct = d >> 4, cl = d & 15;
      int addr;
      if (key < 192) addr = (((ct * 6 + (key >> 5)) * 4 + ((key >> 3) & 3)) * 16 + cl) * 8 + (key & 7);
      else           addr = 12288 + ((ct * 2 + ((key >> 3) & 1)) * 16 + cl) * 8 + (key & 7);
      Vt[addr] = (unsigned short)v[i];
    }
  }
  // zero Vt tail granules for keys 200..207 (never staged)
  if (tid < 64) {
    const int ct = tid >> 4, cl = tid & 15;
    *(bf16x8*)(Vt + 12288 + ((ct * 2 + 1) * 16 + cl) * 8) = (bf16x8)0;
  }
  __syncthreads();
  unsigned short* Pw = Ps + w * 3328;

#pragma unroll
  for (int it = 0; it < 4; ++it) {
    // snake assignment: per-wave chunk list via closed forms
    const int c = (it == 0) ? (12 - w) : (it == 1) ? (5 + w) : (it == 2) ? (4 - w)
                                                                         : (w == 3 ? 0 : -1);
    if (c < 0) continue;
    const int q0 = c << 4;
    const int tmax = (c | 1) > 12 ? 12 : (c | 1);
    const int ktm = c >> 1;

    int qr = q0 + ln; if (qr > S - 1) qr = S - 1;
    const unsigned short* qp = Q + base + (size_t)qr * D + kb * 8;
    const bf16x8 aq0 = *(const bf16x8*)(qp);
    const bf16x8 aq1 = *(const bf16x8*)(qp + 32);
    f32x4 sc[13];
#pragma unroll
    for (int t = 0; t < 13; ++t) {
      if (t <= tmax) {
        f32x4 a = {0.f, 0.f, 0.f, 0.f};
        a = __builtin_amdgcn_mfma_f32_16x16x32_bf16(aq0, *(const bf16x8*)(Ks + (t * 2 + 0) * 512 + lane * 8), a, 0, 0, 0);
        a = __builtin_amdgcn_mfma_f32_16x16x32_bf16(aq1, *(const bf16x8*)(Ks + (t * 2 + 1) * 512 + lane * 8), a, 0, 0, 0);
        sc[t] = a;
      }
    }
    float inv[4];
#pragma unroll
    for (int r = 0; r < 4; ++r) {
      const int q = q0 + kb * 4 + r;
      const int qrow = kb * 4 + r;
      float m = -1e30f;
#pragma unroll
      for (int t = 0; t < 13; ++t) {
        if (t <= tmax) {
          const int j = t * 16 + ln;
          float s = sc[t][r];   // Q pre-scaled
          s = (j <= q) ? s : -1e30f;
          sc[t][r] = s;
          m = fmaxf(m, s);
        }
      }
      m = fmaxf(m, __shfl_xor(m, 1));
      m = fmaxf(m, __shfl_xor(m, 2));
      m = fmaxf(m, __shfl_xor(m, 4));
      m = fmaxf(m, __shfl_xor(m, 8));
      float sm = 0.f;
#pragma unroll
      for (int t = 0; t < 13; ++t) {
        if (t <= tmax) {
          const float e = __expf(sc[t][r] - m);
          sm += e;
          int addr;
          if (t < 12) addr = (((t >> 1) * 4 + ((2 * t + (ln >> 3)) & 3)) * 16 + qrow) * 8 + (ln & 7);
          else        addr = 3072 + ((ln >> 3) * 16 + qrow) * 8 + (ln & 7);
          Pw[addr] = f2b(e);
        }
      }
      sm += __shfl_xor(sm, 1);
      sm += __shfl_xor(sm, 2);
      sm += __shfl_xor(sm, 4);
      sm += __shfl_xor(sm, 8);
      inv[r] = 1.f / sm;
    }
#pragma unroll
    for (int ct = 0; ct < 4; ++ct) {
      f32x4 a = {0.f, 0.f, 0.f, 0.f};
#pragma unroll
      for (int kt = 0; kt < 6; ++kt) {
        if (kt <= ktm) {
          const bf16x8 pa = *(const bf16x8*)(Pw + ((kt * 4 + kb) * 16 + ln) * 8);
          const bf16x8 vb = *(const bf16x8*)(Vt + (((ct * 6 + kt) * 4 + kb) * 16 + ln) * 8);
          a = __builtin_amdgcn_mfma_f32_16x16x32_bf16(pa, vb, a, 0, 0, 0);
        }
      }
      if (c == 12) {
        bf16x8 pa = (bf16x8)0, vb = (bf16x8)0;
        if (kb < 2) {
          pa = *(const bf16x8*)(Pw + 3072 + (kb * 16 + ln) * 8);
          vb = *(const bf16x8*)(Vt + 12288 + ((ct * 2 + kb) * 16 + ln) * 8);
        }
        a = __builtin_amdgcn_mfma_f32_16x16x32_bf16(pa, vb, a, 0, 0, 0);
      }
#pragma unroll
      for (int r = 0; r < 4; ++r) {
        const int q = q0 + kb * 4 + r;
        if (q < S) O[base + (size_t)q * D + ct * 16 + ln] = f2b(a[r] * inv[r]);
      }
    }
  }
}

// ---------------------------------------------------------------------------
extern "C" void kernel_launch(void* const* d_in, const int* in_sizes, int n_in,
                              void* d_out, int out_size, void* d_ws, size_t ws_size,
                              hipStream_t stream) {
  const int* ids        = (const int*)d_in[0];
  const float* item_emb = (const float*)d_in[1];
  const float* pos_emb  = (const float*)d_in[2];
  const float* ln1_g    = (const float*)d_in[3];
  const float* ln1_b    = (const float*)d_in[4];
  const float* wq       = (const float*)d_in[5];
  const float* bq       = (const float*)d_in[6];
  const float* wk       = (const float*)d_in[7];
  const float* bk       = (const float*)d_in[8];
  const float* wv       = (const float*)d_in[9];
  const float* bv       = (const float*)d_in[10];
  const float* ln2_g    = (const float*)d_in[11];
  const float* ln2_b    = (const float*)d_in[12];
  const float* wd       = (const float*)d_in[13];
  const float* bd       = (const float*)d_in[14];
  const float* seq_g    = (const float*)d_in[15];
  const float* seq_b    = (const float*)d_in[16];
  const float* w_out    = (const float*)d_in[17];
  float* out = (float*)d_out;

  // ---- workspace layout (bytes), end = 368,312,320 ----
  char* wsb = (char*)d_ws;
  unsigned short* seq_bf = (unsigned short*)(wsb + 0);
  unsigned short* x_bf   = (unsigned short*)(wsb + 52428800);
  unsigned short* q_bf   = (unsigned short*)(wsb + 104857600);  // q, then t
  unsigned short* k_bf   = (unsigned short*)(wsb + 157286400);
  unsigned short* v_bf   = (unsigned short*)(wsb + 209715200);
  unsigned short* o_bf   = (unsigned short*)(wsb + 262144000);
  unsigned short* x2b    = (unsigned short*)(wsb + 314572800);
  unsigned short* wtb    = (unsigned short*)(wsb + 367001600);  // 1,048,576 B
  unsigned short* semb   = (unsigned short*)(wsb + 368050176);  // 262,144 B

  const int M = B * S;  // 102400
  const int ln_grid = (M + 3) / 4;

  cvt_wt_k<<<512, 256, 0, stream>>>(wq, wk, wv, wd, wtb);
  embed_ln_k<<<ln_grid, 256, 0, stream>>>(ids, item_emb, pos_emb, ln1_g, ln1_b, seq_bf, x_bf);

  for (int blk = 0; blk < 2; ++blk) {
    const float* l2g = ln2_g + blk * D;
    const float* l2b = ln2_b + blk * D;
    const unsigned short* WT = wtb + (size_t)blk * 4 * 65536;  // order: q,k,v,d

    bgemm2_k<0, 0, 0><<<800, 512, 0, stream>>>(seq_bf, WT + 1 * 65536, bk + blk * D, k_bf,
                                               nullptr, nullptr, 1.f, nullptr, nullptr, nullptr);
    bgemm2_k<0, 0, 0><<<800, 512, 0, stream>>>(seq_bf, WT + 2 * 65536, bv + blk * D, v_bf,
                                               nullptr, nullptr, 1.f, nullptr, nullptr, nullptr);
    bgemm2_k<0, 0, 0><<<800, 512, 0, stream>>>(x_bf, WT + 0 * 65536, bq + blk * D, q_bf,
                                               nullptr, nullptr, SCALE, nullptr, nullptr, nullptr);
    attn_k<<<B * H, 256, 0, stream>>>(q_bf, k_bf, v_bf, o_bf);
    ln2x2_k<<<ln_grid, 256, 0, stream>>>(x_bf, o_bf, l2g, l2b, x2b, q_bf, M);
    if (blk == 0) {
      bgemm2_k<1, 1, 1><<<800, 512, 0, stream>>>(q_bf, WT + 3 * 65536, bd + blk * D, seq_bf,
                                                 x2b, ids, 1.f, ln1_g + D, ln1_b + D, x_bf);
    } else {
      bgemm2_k<1, 1, 0><<<800, 512, 0, stream>>>(q_bf, WT + 3 * 65536, bd + blk * D, seq_bf,
                                                 x2b, ids, 1.f, nullptr, nullptr, nullptr);
    }
  }

  ln_bf_k<<<(B + 3) / 4, 256, 0, stream>>>(seq_bf + (size_t)(S - 1) * D, (size_t)S * D,
                                           seq_g, seq_b, semb, B);
  bgemm3_k<<<dim3(4, 782), 256, 0, stream>>>(semb, w_out, out, B, NI);
}

// Round 10
// 736.484 us; speedup vs baseline: 1.0600x; 1.0600x over previous
//
#include <hip/hip_runtime.h>
#include <hip/hip_bf16.h>
#include <cstdint>
#include <cstddef>

namespace {
constexpr int B = 512, S = 200, D = 256, H = 4, DH = 64, NI = 100000;
constexpr float EPS = 1e-3f;
constexpr float SCALE = 0.125f;  // 1/sqrt(DH)
}

typedef __attribute__((ext_vector_type(8))) short bf16x8;
typedef __attribute__((ext_vector_type(4))) float f32x4;

__device__ inline unsigned short f2b(float f) {
  union { float f; unsigned int u; } v; v.f = f;
  unsigned int r = v.u + 0x7FFFu + ((v.u >> 16) & 1u);
  return (unsigned short)(r >> 16);
}

__device__ inline float b2f(unsigned short u) {
  union { unsigned int i; float f; } x; x.i = (unsigned int)u << 16; return x.f;
}

__device__ inline bf16x8 pack8(float4 a, float4 b) {
  bf16x8 r;
  r[0] = (short)f2b(a.x); r[1] = (short)f2b(a.y); r[2] = (short)f2b(a.z); r[3] = (short)f2b(a.w);
  r[4] = (short)f2b(b.x); r[5] = (short)f2b(b.y); r[6] = (short)f2b(b.z); r[7] = (short)f2b(b.w);
  return r;
}

__device__ inline ushort4 pack4(float4 a) {
  ushort4 r;
  r.x = f2b(a.x); r.y = f2b(a.y); r.z = f2b(a.z); r.w = f2b(a.w);
  return r;
}

__device__ inline float4 unpack4(ushort4 u) {
  float4 r; r.x = b2f(u.x); r.y = b2f(u.y); r.z = b2f(u.z); r.w = b2f(u.w); return r;
}

__device__ inline void gload_lds16(const unsigned short* g, unsigned short* l) {
  __builtin_amdgcn_global_load_lds((const __attribute__((address_space(1))) void*)g,
                                   (__attribute__((address_space(3))) void*)l, 16, 0, 0);
}

// ------- hidden weights [K][N] fp32 -> WT bf16 [w][N][K], w = blk*4+{q,k,v,d}
__global__ void cvt_wt_k(const float* __restrict__ wq, const float* __restrict__ wk,
                         const float* __restrict__ wv, const float* __restrict__ wd,
                         unsigned short* __restrict__ dst) {
  const int t = blockIdx.x * 256 + threadIdx.x;  // 131072 total
  const int w = t >> 14, rem = t & 16383;
  const int k = rem >> 6, n4 = (rem & 63) * 4;
  const int blk = w >> 2, which = w & 3;
  const float* src = (which == 0 ? wq : which == 1 ? wk : which == 2 ? wv : wd) + blk * 65536;
  const float4 v = *(const float4*)(src + k * 256 + n4);
  unsigned short* d = dst + w * 65536;
  d[(n4 + 0) * 256 + k] = f2b(v.x);
  d[(n4 + 1) * 256 + k] = f2b(v.y);
  d[(n4 + 2) * 256 + k] = f2b(v.z);
  d[(n4 + 3) * 256 + k] = f2b(v.w);
}

// ------- embed + pos, fused with ln1 of layer 0: wave-per-row --------------
__global__ __launch_bounds__(256) void embed_ln_k(const int* __restrict__ ids,
                                                  const float* __restrict__ ie,
                                                  const float* __restrict__ pe,
                                                  const float* __restrict__ g1,
                                                  const float* __restrict__ b1,
                                                  unsigned short* __restrict__ seq_bf,
                                                  unsigned short* __restrict__ x_bf) {
  const int row = blockIdx.x * 4 + (threadIdx.x >> 6);
  const int lane = threadIdx.x & 63;
  const int id = ids[row];
  const int s = row % S;
  float4 v = *(const float4*)(ie + (size_t)id * D + (lane << 2));
  const float4 p = *(const float4*)(pe + (size_t)s * D + (lane << 2));
  v.x += p.x; v.y += p.y; v.z += p.z; v.w += p.w;
  *(ushort4*)(seq_bf + (size_t)row * D + (lane << 2)) = pack4(v);
  const float4 vb = unpack4(pack4(v));
  float su = vb.x + vb.y + vb.z + vb.w;
  float ss = vb.x * vb.x + vb.y * vb.y + vb.z * vb.z + vb.w * vb.w;
#pragma unroll
  for (int off = 32; off; off >>= 1) {
    su += __shfl_xor(su, off);
    ss += __shfl_xor(ss, off);
  }
  const float mean = su * (1.f / D);
  const float rs = rsqrtf(ss * (1.f / D) - mean * mean + EPS);
  const float4 gv = *(const float4*)(g1 + (lane << 2));
  const float4 bv = *(const float4*)(b1 + (lane << 2));
  float4 o;
  o.x = (vb.x - mean) * rs * gv.x + bv.x;
  o.y = (vb.y - mean) * rs * gv.y + bv.y;
  o.z = (vb.z - mean) * rs * gv.z + bv.z;
  o.w = (vb.w - mean) * rs * gv.w + bv.w;
  *(ushort4*)(x_bf + (size_t)row * D + (lane << 2)) = pack4(o);
}

// ---------------- wave-per-row LayerNorm, bf16 in -> bf16 out (semb) -------
__global__ __launch_bounds__(256) void ln_bf_k(const unsigned short* __restrict__ in,
                                               size_t in_stride,
                                               const float* __restrict__ g, const float* __restrict__ b,
                                               unsigned short* __restrict__ outp, int nrows) {
  const int row = blockIdx.x * 4 + (threadIdx.x >> 6);
  if (row >= nrows) return;
  const int lane = threadIdx.x & 63;
  const float4 v = unpack4(*(const ushort4*)(in + (size_t)row * in_stride + (lane << 2)));
  float s = v.x + v.y + v.z + v.w;
  float ss = v.x * v.x + v.y * v.y + v.z * v.z + v.w * v.w;
#pragma unroll
  for (int off = 32; off; off >>= 1) {
    s += __shfl_xor(s, off);
    ss += __shfl_xor(ss, off);
  }
  const float mean = s * (1.f / D);
  const float rs = rsqrtf(ss * (1.f / D) - mean * mean + EPS);
  const float4 gv = *(const float4*)(g + (lane << 2));
  const float4 bv = *(const float4*)(b + (lane << 2));
  float4 o;
  o.x = (v.x - mean) * rs * gv.x + bv.x;
  o.y = (v.y - mean) * rs * gv.y + bv.y;
  o.z = (v.z - mean) * rs * gv.z + bv.z;
  o.w = (v.w - mean) * rs * gv.w + bv.w;
  *(ushort4*)(outp + (size_t)row * D + (lane << 2)) = pack4(o);
}

// -------- QKV GEMM: C[M,256] = A[M,256] @ Wt[256,256]^T (+bias), bf16 out --
__global__ __launch_bounds__(512) void bgemm2_k(const unsigned short* __restrict__ A,
                                                const unsigned short* __restrict__ Wt,
                                                const float* __restrict__ bias,
                                                unsigned short* __restrict__ Cbf, float osc) {
  __shared__ unsigned short As[128 * 64];
  __shared__ unsigned short Bs[256 * 64];
  const int tid = threadIdx.x, w = tid >> 6, lane = tid & 63;
  const int kb = lane >> 4, ln = lane & 15;
  const int m0 = blockIdx.x * 128;
  const int wm = w & 1, wn = w >> 1;

  f32x4 acc[4][4];
#pragma unroll
  for (int i = 0; i < 4; ++i)
#pragma unroll
    for (int j = 0; j < 4; ++j) acc[i][j] = (f32x4){0.f, 0.f, 0.f, 0.f};

  for (int ks = 0; ks < 4; ++ks) {
    const int ko = ks * 64;
#pragma unroll
    for (int r = 0; r < 2; ++r) {
      const int g = (w * 2 + r) * 64 + lane;
      const int row = g >> 3, gc = g & 7;
      gload_lds16(A + (size_t)(m0 + row) * 256 + ko + ((gc ^ (row & 7)) << 3),
                  As + (size_t)(w * 2 + r) * 512);
    }
#pragma unroll
    for (int r = 0; r < 4; ++r) {
      const int g = (w * 4 + r) * 64 + lane;
      const int row = g >> 3, gc = g & 7;
      gload_lds16(Wt + (size_t)row * 256 + ko + ((gc ^ (row & 7)) << 3),
                  Bs + (size_t)(w * 4 + r) * 512);
    }
    __syncthreads();
#pragma unroll
    for (int h = 0; h < 2; ++h) {
      bf16x8 af[4], bfr[4];
#pragma unroll
      for (int i = 0; i < 4; ++i) {
        const int ar = wm * 64 + i * 16 + ln;
        af[i] = *(const bf16x8*)(As + ar * 64 + (((h * 64 + kb * 16) ^ ((ar & 7) << 4)) >> 1));
        const int br = wn * 64 + i * 16 + ln;
        bfr[i] = *(const bf16x8*)(Bs + br * 64 + (((h * 64 + kb * 16) ^ ((br & 7) << 4)) >> 1));
      }
#pragma unroll
      for (int i = 0; i < 4; ++i)
#pragma unroll
        for (int j = 0; j < 4; ++j)
          acc[i][j] = __builtin_amdgcn_mfma_f32_16x16x32_bf16(af[i], bfr[j], acc[i][j], 0, 0, 0);
    }
    __syncthreads();
  }

  const int crow0 = m0 + wm * 64 + kb * 4;
  const int ccol0 = wn * 64 + ln;
#pragma unroll
  for (int j = 0; j < 4; ++j) {
    const int col = ccol0 + j * 16;
    const float bj = bias[col];
#pragma unroll
    for (int i = 0; i < 4; ++i) {
#pragma unroll
      for (int r = 0; r < 4; ++r) {
        const int row = crow0 + i * 16 + r;
        Cbf[(size_t)row * 256 + col] = f2b((acc[i][j][r] + bj) * osc);
      }
    }
  }
}

// -------- FFN fused: x2 = x+o ; t = ln2(x2) ; y = relu(t@Wd+bd) ;
//          seq = (y+x2)*mask ; [LN1: x1 = ln1(seq)].  64-row x 256-col tile.
template <int LN1>
__global__ __launch_bounds__(256) void ffn_k(const unsigned short* __restrict__ x_bf,
                                             const unsigned short* __restrict__ o_bf,
                                             const unsigned short* __restrict__ Wt,
                                             const float* __restrict__ bias,
                                             const float* __restrict__ g2,
                                             const float* __restrict__ b2,
                                             const int* __restrict__ ids,
                                             unsigned short* __restrict__ seq_out,
                                             const float* __restrict__ g1,
                                             const float* __restrict__ b1,
                                             unsigned short* __restrict__ x1) {
  __shared__ unsigned short Xt[64 * 256];   // 32 KB swizzled x2 -> t tile
  __shared__ unsigned short Bs[256 * 64];   // 32 KB W chunk per ks
  __shared__ float stats[64][2];            // mu, rs per row
  __shared__ float params[512];             // g2|b2 ; later reused as LN1 red
  const int tid = threadIdx.x, w = tid >> 6, lane = tid & 63;
  const int kb = lane >> 4, ln = lane & 15;
  const int m0 = blockIdx.x * 64;
  const int wn = w;  // 4 waves over 256 cols

  params[tid] = g2[tid & 255];
  params[256 + (tid & 255)] = b2[tid & 255];
  // ---- phase 1: x2 tile (swizzled: byte ^= (row&7)<<4 within 128B chunk) --
#pragma unroll
  for (int it = 0; it < 8; ++it) {
    const int g = it * 256 + tid;
    const int row = g >> 5, gc = g & 31;
    const bf16x8 xv = *(const bf16x8*)(x_bf + (size_t)(m0 + row) * 256 + gc * 8);
    const bf16x8 ov = *(const bf16x8*)(o_bf + (size_t)(m0 + row) * 256 + gc * 8);
    bf16x8 sv;
#pragma unroll
    for (int e = 0; e < 8; ++e)
      sv[e] = (short)f2b(b2f((unsigned short)xv[e]) + b2f((unsigned short)ov[e]));
    *(bf16x8*)(Xt + row * 256 + (((gc * 16) ^ ((row & 7) << 4)) >> 1)) = sv;
  }
  __syncthreads();
  // ---- phase 2: row stats, 4 threads per row ----
  {
    const int srow = tid >> 2, sq = tid & 3;
    float su = 0.f, ssq = 0.f;
#pragma unroll
    for (int gg = 0; gg < 8; ++gg) {
      const int gc = sq * 8 + gg;
      const bf16x8 v = *(const bf16x8*)(Xt + srow * 256 + (((gc * 16) ^ ((srow & 7) << 4)) >> 1));
#pragma unroll
      for (int e = 0; e < 8; ++e) {
        const float f = b2f((unsigned short)v[e]);
        su += f; ssq += f * f;
      }
    }
    su += __shfl_xor(su, 1); ssq += __shfl_xor(ssq, 1);
    su += __shfl_xor(su, 2); ssq += __shfl_xor(ssq, 2);
    if (sq == 0) {
      const float mean = su * (1.f / D);
      stats[srow][0] = mean;
      stats[srow][1] = rsqrtf(ssq * (1.f / D) - mean * mean + EPS);
    }
  }
  __syncthreads();
  // ---- phase 2b: extract epilogue x2 into regs (before in-place transform)
  float ep[4][4][4];
  const int ccl = wn * 64 + ln;
#pragma unroll
  for (int i = 0; i < 4; ++i)
#pragma unroll
    for (int j = 0; j < 4; ++j)
#pragma unroll
      for (int r = 0; r < 4; ++r) {
        const int rr = i * 16 + kb * 4 + r;
        const int col = ccl + j * 16;
        ep[i][j][r] = b2f(Xt[rr * 256 + (((col * 2) ^ ((rr & 7) << 4)) >> 1)]);
      }
  __syncthreads();
  // ---- phase 3: in-place transform x2 -> t = ln2(x2) ----
#pragma unroll
  for (int it = 0; it < 8; ++it) {
    const int g = it * 256 + tid;
    const int row = g >> 5, gc = g & 31;
    const int idx = row * 256 + (((gc * 16) ^ ((row & 7) << 4)) >> 1);
    const bf16x8 v = *(const bf16x8*)(Xt + idx);
    const float mu = stats[row][0], rs = stats[row][1];
    bf16x8 t;
#pragma unroll
    for (int e = 0; e < 8; ++e) {
      const int k = gc * 8 + e;
      t[e] = (short)f2b((b2f((unsigned short)v[e]) - mu) * rs * params[k] + params[256 + k]);
    }
    *(bf16x8*)(Xt + idx) = t;
  }
  __syncthreads();
  // ---- phase 4: K-loop (A = resident t-tile; B staged per ks) ----
  f32x4 acc[4][4];
#pragma unroll
  for (int i = 0; i < 4; ++i)
#pragma unroll
    for (int j = 0; j < 4; ++j) acc[i][j] = (f32x4){0.f, 0.f, 0.f, 0.f};

  for (int ks = 0; ks < 4; ++ks) {
#pragma unroll
    for (int r = 0; r < 8; ++r) {
      const int g = (w * 8 + r) * 64 + lane;
      const int row = g >> 3, gc = g & 7;
      gload_lds16(Wt + (size_t)row * 256 + ks * 64 + ((gc ^ (row & 7)) << 3),
                  Bs + (size_t)(w * 8 + r) * 512);
    }
    __syncthreads();
#pragma unroll
    for (int h = 0; h < 2; ++h) {
      bf16x8 af[4], bfr[4];
#pragma unroll
      for (int i = 0; i < 4; ++i) {
        const int ar = i * 16 + ln;
        af[i] = *(const bf16x8*)(Xt + ar * 256 +
                                 ((ks * 128 + ((h * 64 + kb * 16) ^ ((ar & 7) << 4))) >> 1));
        const int br = wn * 64 + i * 16 + ln;
        bfr[i] = *(const bf16x8*)(Bs + br * 64 + (((h * 64 + kb * 16) ^ ((br & 7) << 4)) >> 1));
      }
#pragma unroll
      for (int i = 0; i < 4; ++i)
#pragma unroll
        for (int j = 0; j < 4; ++j)
          acc[i][j] = __builtin_amdgcn_mfma_f32_16x16x32_bf16(af[i], bfr[j], acc[i][j], 0, 0, 0);
    }
    __syncthreads();
  }
  // ---- epilogue ----
  float mk[4][4];
#pragma unroll
  for (int i = 0; i < 4; ++i)
#pragma unroll
    for (int r = 0; r < 4; ++r)
      mk[i][r] = (ids[m0 + i * 16 + kb * 4 + r] != NI) ? 1.f : 0.f;
#pragma unroll
  for (int j = 0; j < 4; ++j) {
    const int col = ccl + j * 16;
    const float bj = bias[col];
#pragma unroll
    for (int i = 0; i < 4; ++i) {
#pragma unroll
      for (int r = 0; r < 4; ++r) {
        const int grow = m0 + i * 16 + kb * 4 + r;
        float v = fmaxf(acc[i][j][r] + bj, 0.f);
        v = (v + ep[i][j][r]) * mk[i][r];
        const unsigned short vb = f2b(v);
        seq_out[(size_t)grow * 256 + col] = vb;
        if (LN1) acc[i][j][r] = b2f(vb);
      }
    }
  }
  if (LN1) {
    float s_[4][4], ss_[4][4];
#pragma unroll
    for (int i = 0; i < 4; ++i)
#pragma unroll
      for (int r = 0; r < 4; ++r) {
        float s = 0.f, ss = 0.f;
#pragma unroll
        for (int j = 0; j < 4; ++j) { const float v = acc[i][j][r]; s += v; ss += v * v; }
#pragma unroll
        for (int off = 1; off < 16; off <<= 1) {
          s += __shfl_xor(s, off);
          ss += __shfl_xor(ss, off);
        }
        s_[i][r] = s; ss_[i][r] = ss;
      }
    float* red = params;  // 64 rows x 4 wn x 2 = 512 floats (params now dead)
    __syncthreads();
    if (ln == 0) {
#pragma unroll
      for (int i = 0; i < 4; ++i)
#pragma unroll
        for (int r = 0; r < 4; ++r) {
          const int rt = i * 16 + kb * 4 + r;
          red[rt * 8 + wn * 2 + 0] = s_[i][r];
          red[rt * 8 + wn * 2 + 1] = ss_[i][r];
        }
    }
    __syncthreads();
#pragma unroll
    for (int i = 0; i < 4; ++i)
#pragma unroll
      for (int r = 0; r < 4; ++r) {
        const int rt = i * 16 + kb * 4 + r;
        float Sv = 0.f, SS = 0.f;
#pragma unroll
        for (int q = 0; q < 4; ++q) { Sv += red[rt * 8 + q * 2]; SS += red[rt * 8 + q * 2 + 1]; }
        const float mean = Sv * (1.f / D);
        s_[i][r] = mean;
        ss_[i][r] = rsqrtf(SS * (1.f / D) - mean * mean + EPS);
      }
#pragma unroll
    for (int j = 0; j < 4; ++j) {
      const int col = ccl + j * 16;
      const float gc = g1[col], bc = b1[col];
#pragma unroll
      for (int i = 0; i < 4; ++i) {
#pragma unroll
        for (int r = 0; r < 4; ++r) {
          const int grow = m0 + i * 16 + kb * 4 + r;
          const float xv = (acc[i][j][r] - s_[i][r]) * ss_[i][r] * gc + bc;
          x1[(size_t)grow * 256 + col] = f2b(xv);
        }
      }
    }
  }
}

// -------- logits GEMM: one block per 128-col w_out panel, B resident -------
__global__ __launch_bounds__(256) void logits_k(const unsigned short* __restrict__ A,
                                                const float* __restrict__ Wf,
                                                float* __restrict__ C) {
  __shared__ unsigned short Bs[128 * 256];  // 64 KB resident panel (bf16, swizzled)
  __shared__ unsigned short As[128 * 256];  // 64 KB per m-group
  const int tid = threadIdx.x, w = tid >> 6, lane = tid & 63;
  const int kb = lane >> 4, ln = lane & 15;
  const int wm = w & 1, wn = w >> 1;
  const int n0 = blockIdx.x * 128;
  // stage B panel once: f32 -> bf16, swizzled
#pragma unroll
  for (int it = 0; it < 16; ++it) {
    const int g = it * 256 + tid;
    const int row = g >> 5, gc = g & 31;
    int br = n0 + row; if (br > NI - 1) br = NI - 1;
    const float* src = Wf + (size_t)br * 256 + gc * 8;
    const float4 f0 = *(const float4*)src;
    const float4 f1 = *(const float4*)(src + 4);
    *(bf16x8*)(Bs + row * 256 + (((gc * 16) ^ ((row & 7) << 4)) >> 1)) = pack8(f0, f1);
  }
  for (int m = 0; m < 4; ++m) {
    const int m0 = m * 128;
    // stage A (semb bf16) via global_load_lds: linear dest, inv-swizzled src
#pragma unroll
    for (int it = 0; it < 16; ++it) {
      const int g = it * 256 + w * 64 + lane;
      const int row = g >> 5, gc = g & 31;
      gload_lds16(A + (size_t)(m0 + row) * 256 + (((gc * 16) ^ ((row & 7) << 4)) >> 1),
                  As + (size_t)(it * 256 + w * 64) * 8);
    }
    __syncthreads();
    f32x4 acc[4][4];
#pragma unroll
    for (int i = 0; i < 4; ++i)
#pragma unroll
      for (int j = 0; j < 4; ++j) acc[i][j] = (f32x4){0.f, 0.f, 0.f, 0.f};
#pragma unroll
    for (int ks = 0; ks < 4; ++ks) {
#pragma unroll
      for (int h = 0; h < 2; ++h) {
        bf16x8 af[4], bfr[4];
#pragma unroll
        for (int i = 0; i < 4; ++i) {
          const int ar = wm * 64 + i * 16 + ln;
          af[i] = *(const bf16x8*)(As + ar * 256 +
                                   ((ks * 128 + ((h * 64 + kb * 16) ^ ((ar & 7) << 4))) >> 1));
          const int br = wn * 64 + i * 16 + ln;
          bfr[i] = *(const bf16x8*)(Bs + br * 256 +
                                    ((ks * 128 + ((h * 64 + kb * 16) ^ ((br & 7) << 4))) >> 1));
        }
#pragma unroll
        for (int i = 0; i < 4; ++i)
#pragma unroll
          for (int j = 0; j < 4; ++j)
            acc[i][j] = __builtin_amdgcn_mfma_f32_16x16x32_bf16(af[i], bfr[j], acc[i][j], 0, 0, 0);
      }
    }
    const int crow0 = m0 + wm * 64 + kb * 4;
    const int ccol0 = n0 + wn * 64 + ln;
#pragma unroll
    for (int j = 0; j < 4; ++j) {
      const int col = ccol0 + j * 16;
      if (col >= NI) continue;
#pragma unroll
      for (int i = 0; i < 4; ++i) {
#pragma unroll
        for (int r = 0; r < 4; ++r) {
          const int row = crow0 + i * 16 + r;
          C[(size_t)row * NI + col] = acc[i][j][r];
        }
      }
    }
    __syncthreads();  // all reads done before next m-group restage
  }
}

// ---------------- MFMA causal attention (r9, unchanged) --------------------
__global__ __launch_bounds__(256) void attn_k(const unsigned short* __restrict__ Q,
                                              const unsigned short* __restrict__ Kg,
                                              const unsigned short* __restrict__ Vg,
                                              unsigned short* __restrict__ O) {
  __shared__ unsigned short Ks[13312];
  __shared__ unsigned short Vt[13312];
  __shared__ unsigned short Ps[4 * 3328];
  const int b = blockIdx.x >> 2;
  const int h = blockIdx.x & 3;
  const int tid = threadIdx.x, w = tid >> 6, lane = tid & 63;
  const int kb = lane >> 4, ln = lane & 15;
  const size_t base = (size_t)b * S * D + h * DH;

  for (int s = w; s < 26; s += 4) {
    const int t = s >> 1, h2 = s & 1;
    int krow = t * 16 + ln; if (krow > S - 1) krow = S - 1;
    gload_lds16(Kg + base + (size_t)krow * D + h2 * 32 + kb * 8, Ks + s * 512);
  }
  for (int g = tid; g < 200 * 8; g += 256) {
    const int key = g >> 3, d0 = (g & 7) * 8;
    const bf16x8 v = *(const bf16x8*)(Vg + base + (size_t)key * D + d0);
#pragma unroll
    for (int i = 0; i < 8; ++i) {
      const int d = d0 + i, ct = d >> 4, cl = d & 15;
      int addr;
      if (key < 192) addr = (((ct * 6 + (key >> 5)) * 4 + ((key >> 3) & 3)) * 16 + cl) * 8 + (key & 7);
      else           addr = 12288 + ((ct * 2 + ((key >> 3) & 1)) * 16 + cl) * 8 + (key & 7);
      Vt[addr] = (unsigned short)v[i];
    }
  }
  if (tid < 64) {
    const int ct = tid >> 4, cl = tid & 15;
    *(bf16x8*)(Vt + 12288 + ((ct * 2 + 1) * 16 + cl) * 8) = (bf16x8)0;
  }
  __syncthreads();
  unsigned short* Pw = Ps + w * 3328;

#pragma unroll
  for (int it = 0; it < 4; ++it) {
    const int c = (it == 0) ? (12 - w) : (it == 1) ? (5 + w) : (it == 2) ? (4 - w)
                                                                         : (w == 3 ? 0 : -1);
    if (c < 0) continue;
    const int q0 = c << 4;
    const int tmax = (c | 1) > 12 ? 12 : (c | 1);
    const int ktm = c >> 1;

    int qr = q0 + ln; if (qr > S - 1) qr = S - 1;
    const unsigned short* qp = Q + base + (size_t)qr * D + kb * 8;
    const bf16x8 aq0 = *(const bf16x8*)(qp);
    const bf16x8 aq1 = *(const bf16x8*)(qp + 32);
    f32x4 sc[13];
#pragma unroll
    for (int t = 0; t < 13; ++t) {
      if (t <= tmax) {
        f32x4 a = {0.f, 0.f, 0.f, 0.f};
        a = __builtin_amdgcn_mfma_f32_16x16x32_bf16(aq0, *(const bf16x8*)(Ks + (t * 2 + 0) * 512 + lane * 8), a, 0, 0, 0);
        a = __builtin_amdgcn_mfma_f32_16x16x32_bf16(aq1, *(const bf16x8*)(Ks + (t * 2 + 1) * 512 + lane * 8), a, 0, 0, 0);
        sc[t] = a;
      }
    }
    float inv[4];
#pragma unroll
    for (int r = 0; r < 4; ++r) {
      const int q = q0 + kb * 4 + r;
      const int qrow = kb * 4 + r;
      float m = -1e30f;
#pragma unroll
      for (int t = 0; t < 13; ++t) {
        if (t <= tmax) {
          const int j = t * 16 + ln;
          float s = sc[t][r];
          s = (j <= q) ? s : -1e30f;
          sc[t][r] = s;
          m = fmaxf(m, s);
        }
      }
      m = fmaxf(m, __shfl_xor(m, 1));
      m = fmaxf(m, __shfl_xor(m, 2));
      m = fmaxf(m, __shfl_xor(m, 4));
      m = fmaxf(m, __shfl_xor(m, 8));
      float sm = 0.f;
#pragma unroll
      for (int t = 0; t < 13; ++t) {
        if (t <= tmax) {
          const float e = __expf(sc[t][r] - m);
          sm += e;
          int addr;
          if (t < 12) addr = (((t >> 1) * 4 + ((2 * t + (ln >> 3)) & 3)) * 16 + qrow) * 8 + (ln & 7);
          else        addr = 3072 + ((ln >> 3) * 16 + qrow) * 8 + (ln & 7);
          Pw[addr] = f2b(e);
        }
      }
      sm += __shfl_xor(sm, 1);
      sm += __shfl_xor(sm, 2);
      sm += __shfl_xor(sm, 4);
      sm += __shfl_xor(sm, 8);
      inv[r] = 1.f / sm;
    }
#pragma unroll
    for (int ct = 0; ct < 4; ++ct) {
      f32x4 a = {0.f, 0.f, 0.f, 0.f};
#pragma unroll
      for (int kt = 0; kt < 6; ++kt) {
        if (kt <= ktm) {
          const bf16x8 pa = *(const bf16x8*)(Pw + ((kt * 4 + kb) * 16 + ln) * 8);
          const bf16x8 vb = *(const bf16x8*)(Vt + (((ct * 6 + kt) * 4 + kb) * 16 + ln) * 8);
          a = __builtin_amdgcn_mfma_f32_16x16x32_bf16(pa, vb, a, 0, 0, 0);
        }
      }
      if (c == 12) {
        bf16x8 pa = (bf16x8)0, vb = (bf16x8)0;
        if (kb < 2) {
          pa = *(const bf16x8*)(Pw + 3072 + (kb * 16 + ln) * 8);
          vb = *(const bf16x8*)(Vt + 12288 + ((ct * 2 + kb) * 16 + ln) * 8);
        }
        a = __builtin_amdgcn_mfma_f32_16x16x32_bf16(pa, vb, a, 0, 0, 0);
      }
#pragma unroll
      for (int r = 0; r < 4; ++r) {
        const int q = q0 + kb * 4 + r;
        if (q < S) O[base + (size_t)q * D + ct * 16 + ln] = f2b(a[r] * inv[r]);
      }
    }
  }
}

// ---------------------------------------------------------------------------
extern "C" void kernel_launch(void* const* d_in, const int* in_sizes, int n_in,
                              void* d_out, int out_size, void* d_ws, size_t ws_size,
                              hipStream_t stream) {
  const int* ids        = (const int*)d_in[0];
  const float* item_emb = (const float*)d_in[1];
  const float* pos_emb  = (const float*)d_in[2];
  const float* ln1_g    = (const float*)d_in[3];
  const float* ln1_b    = (const float*)d_in[4];
  const float* wq       = (const float*)d_in[5];
  const float* bq       = (const float*)d_in[6];
  const float* wk       = (const float*)d_in[7];
  const float* bk       = (const float*)d_in[8];
  const float* wv       = (const float*)d_in[9];
  const float* bv       = (const float*)d_in[10];
  const float* ln2_g    = (const float*)d_in[11];
  const float* ln2_b    = (const float*)d_in[12];
  const float* wd       = (const float*)d_in[13];
  const float* bd       = (const float*)d_in[14];
  const float* seq_g    = (const float*)d_in[15];
  const float* seq_b    = (const float*)d_in[16];
  const float* w_out    = (const float*)d_in[17];
  float* out = (float*)d_out;

  // ---- workspace layout (bytes) ----
  char* wsb = (char*)d_ws;
  unsigned short* seq_bf = (unsigned short*)(wsb + 0);
  unsigned short* x_bf   = (unsigned short*)(wsb + 52428800);
  unsigned short* q_bf   = (unsigned short*)(wsb + 104857600);
  unsigned short* k_bf   = (unsigned short*)(wsb + 157286400);
  unsigned short* v_bf   = (unsigned short*)(wsb + 209715200);
  unsigned short* o_bf   = (unsigned short*)(wsb + 262144000);
  unsigned short* wtb    = (unsigned short*)(wsb + 314572800);  // 1,048,576 B
  unsigned short* semb   = (unsigned short*)(wsb + 315621376);  // 262,144 B

  const int M = B * S;  // 102400
  const int ln_grid = (M + 3) / 4;

  cvt_wt_k<<<512, 256, 0, stream>>>(wq, wk, wv, wd, wtb);
  embed_ln_k<<<ln_grid, 256, 0, stream>>>(ids, item_emb, pos_emb, ln1_g, ln1_b, seq_bf, x_bf);

  for (int blk = 0; blk < 2; ++blk) {
    const unsigned short* WT = wtb + (size_t)blk * 4 * 65536;  // order: q,k,v,d

    bgemm2_k<<<800, 512, 0, stream>>>(seq_bf, WT + 1 * 65536, bk + blk * D, k_bf, 1.f);
    bgemm2_k<<<800, 512, 0, stream>>>(seq_bf, WT + 2 * 65536, bv + blk * D, v_bf, 1.f);
    bgemm2_k<<<800, 512, 0, stream>>>(x_bf, WT + 0 * 65536, bq + blk * D, q_bf, SCALE);
    attn_k<<<B * H, 256, 0, stream>>>(q_bf, k_bf, v_bf, o_bf);
    if (blk == 0) {
      ffn_k<1><<<1600, 256, 0, stream>>>(x_bf, o_bf, WT + 3 * 65536, bd + blk * D,
                                         ln2_g + blk * D, ln2_b + blk * D, ids, seq_bf,
                                         ln1_g + D, ln1_b + D, x_bf);
    } else {
      ffn_k<0><<<1600, 256, 0, stream>>>(x_bf, o_bf, WT + 3 * 65536, bd + blk * D,
                                         ln2_g + blk * D, ln2_b + blk * D, ids, seq_bf,
                                         nullptr, nullptr, nullptr);
    }
  }

  ln_bf_k<<<(B + 3) / 4, 256, 0, stream>>>(seq_bf + (size_t)(S - 1) * D, (size_t)S * D,
                                           seq_g, seq_b, semb, B);
  logits_k<<<782, 256, 0, stream>>>(semb, w_out, out);
}